// Round 2
// baseline (757.180 us; speedup 1.0000x reference)
//
#include <hip/hip_runtime.h>

// ---------------------------------------------------------------------------
// e3nn-style tensor product:  X irreps 64x(l=0,1,2)  (x)  Y irreps 1x(l=0,1,2)
// 19 output paths, per-row out dim 5184, N=32768 rows.
// Memory-bound target (679 MB write + 77 MB read -> ~125 us floor at 6.3 TB/s).
//
// Wigner-3j tables are computed at COMPILE TIME (same fp64 Racah +
// complex->real basis algorithm as the previously-verified runtime w3j_init),
// so the inner loop is pure literal-constant FMAs: no LDS, no w3j_init
// kernel, and all exactly-zero w3j entries removed by constant folding
// (the `if (wv != 0.0f)` folds after full unrolling).
// Previous verified version was LDS-read-throughput bound (1225 ds_read_b32
// per row); this removes all LDS traffic.
// ---------------------------------------------------------------------------

#define NP 19

constexpr int P_L1[NP]  = {0,0,0, 1,1,1,1,1,1,1, 2,2,2,2,2,2,2,2,2};
constexpr int P_L2[NP]  = {0,1,2, 0,1,1,1,2,2,2, 0,1,1,1,2,2,2,2,2};
constexpr int P_L3[NP]  = {0,1,2, 1,0,1,2,1,2,3, 2,1,2,3,0,1,2,3,4};
// output chunk offsets within a row (chunk size 64*d3; total 5184)
constexpr int P_ZOFF[NP] = {0,64,256,576,768,832,1024,1344,1536,1856,2304,2624,2816,3136,3584,3648,3840,4160,4608};
constexpr int XD = 576, YD = 9, ZD = 5184;

// ------------------- compile-time Wigner-3j (mirrors reference) ------------

constexpr double dfact(int n){ double r=1.0; for(int i=2;i<=n;++i) r*=(double)i; return r; }
constexpr double cabs_(double x){ return x<0.0 ? -x : x; }

constexpr double csqrt(double x){
  if (x<=0.0) return 0.0;
  double y = x>1.0 ? x : 1.0;
  for (int i=0;i<50;++i){                      // Newton; early-exit at convergence
    double ny = 0.5*(y + x/y);
    if (ny == y) break;
    y = ny;
  }
  return y;
}

// Condon-Shortley CG <j1 m1 j2 m2 | j3 m3> (Racah) -- exact mirror of _cg()
constexpr double cgc(int j1,int m1,int j2,int m2,int j3,int m3){
  if (m1+m2 != m3) return 0.0;
  double pre = (double)(2*j3+1) * dfact(j3+j1-j2)*dfact(j3-j1+j2)*dfact(j1+j2-j3)/dfact(j1+j2+j3+1);
  pre *= dfact(j3+m3)*dfact(j3-m3)*dfact(j1-m1)*dfact(j1+m1)*dfact(j2-m2)*dfact(j2+m2);
  double s = 0.0;
  for (int k=0;k<=j1+j2-j3;++k){
    int d0=j1+j2-j3-k, d1=j1-m1-k, d2=j2+m2-k, d3=j3-j2+m1+k, d4=j3-j1-m2+k;
    if (d0<0||d1<0||d2<0||d3<0||d4<0) continue;
    double t = 1.0/(dfact(k)*dfact(d0)*dfact(d1)*dfact(d2)*dfact(d3)*dfact(d4));
    s += (k&1) ? -t : t;
  }
  return csqrt(pre)*s;
}

// complex->real SH change of basis Q(l)[r][c] -- exact mirror of _Q()
constexpr void Qv(int l,int r,int c,double& re,double& im){
  re=0.0; im=0.0;
  const double s2 = 0.70710678118654752440;
  if (r==l){ if (c==l) re=1.0; return; }
  if (r>l){ int m=r-l;
    if (c==l-m)      re = s2;
    else if (c==l+m) re = (m&1)? -s2 : s2;     // (-1)^m * s2
  } else { int m=l-r;
    if (c==l-m)      im = s2;                  // i*s2
    else if (c==l+m) im = (m&1)? s2 : -s2;     // -i*(-1)^m*s2
  }
}

struct PathTab { float v[225]; };

// real-basis w3j * alpha for one (l1,l2,l3) path -- exact mirror of w3j_init
constexpr PathTab make_path(int l1,int l2,int l3){
  PathTab t{};
  const int d1=2*l1+1, d2=2*l2+1, d3=2*l3+1;
  double Cre[25]={};
  for (int a=0;a<d1;++a) for (int b=0;b<d2;++b){
    int m1=a-l1, m2=b-l2, m3=-(m1+m2);
    int am3 = m3<0 ? -m3 : m3;
    double v = 0.0;
    if (am3 <= l3){
      v = cgc(l1,m1,l2,m2,l3,-m3) / csqrt((double)(2*l3+1));
      if ((l1-l2-m3)&1) v = -v;                // (-1)^(l1-l2-m3)
    }
    Cre[a*d2+b] = v;
  }
  double Tre[225]={}, Tim[225]={};
  for (int e=0;e<d1*d2*d3;++e){
    int i = e/(d2*d3); int r = e%(d2*d3); int j = r/d3; int k = r%d3;
    double tre=0.0, tim=0.0;
    for (int a=0;a<d1;++a) for (int b=0;b<d2;++b){
      double cr = Cre[a*d2+b];
      if (cr == 0.0) continue;
      int m3 = -((a-l1)+(b-l2));
      int c = m3 + l3;
      if (c < 0 || c >= d3) continue;
      double q1r=0,q1i=0,q2r=0,q2i=0,q3r=0,q3i=0;
      Qv(l1,i,a,q1r,q1i);
      Qv(l2,j,b,q2r,q2i);
      Qv(l3,k,c,q3r,q3i);
      double pr = q1r*q2r - q1i*q2i;
      double pi = q1r*q2i + q1i*q2r;
      tre += (pr*q3r - pi*q3i)*cr;
      tim += (pr*q3i + pi*q3r)*cr;
    }
    Tre[e]=tre; Tim[e]=tim;
  }
  double sre=0.0, sim=0.0;
  for (int e=0;e<d1*d2*d3;++e){ sre += cabs_(Tre[e]); sim += cabs_(Tim[e]); }
  const bool useim = (sim > sre);              // reference picks re if sre>=sim
  const double alpha = csqrt((double)(2*l3+1)); // component-norm factor folded in
  for (int e=0;e<d1*d2*d3;++e){
    double v = useim ? Tim[e] : Tre[e];
    t.v[e] = (float)(v*alpha);
  }
  return t;
}

// one compile-time table per path: each static member is a SEPARATE constexpr
// evaluation, keeping every evaluation well under clang's constexpr-step limit
template<int P> struct PathW { static constexpr PathTab t = make_path(P_L1[P],P_L2[P],P_L3[P]); };

// ------------------------------ main kernel --------------------------------
// one wave per row; lane u = channel (mu=64 == wavefront size).
// All w3j factors fold to inline literals; zero entries are DCE'd.

template<int P>
__device__ __forceinline__ void do_path(float xv0, const float (&xv1)[3], const float (&xv2)[5],
                                        const float (&yv)[9], float* __restrict__ zr, int u){
  constexpr int l1=P_L1[P], l2=P_L2[P], l3=P_L3[P];
  constexpr int d1=2*l1+1, d2=2*l2+1, d3=2*l3+1;
  constexpr int yo = (l2==0) ? 0 : (l2==1 ? 1 : 4);

  float acc[d3];
  #pragma unroll
  for (int k=0;k<d3;++k) acc[k] = 0.f;

  #pragma unroll
  for (int i=0;i<d1;++i){
    const float xi = (l1==0) ? xv0 : (l1==1 ? xv1[i] : xv2[i]);
    #pragma unroll
    for (int j=0;j<d2;++j){
      const float xy = xi * yv[yo+j];          // DCE'd if all wv below are 0
      #pragma unroll
      for (int k=0;k<d3;++k){
        const float wv = PathW<P>::t.v[(i*d2+j)*d3 + k];  // folds to literal
        if (wv != 0.0f)                        // constant-folded branch
          acc[k] = __builtin_fmaf(xy, wv, acc[k]);
      }
    }
  }

  float* zp = zr + P_ZOFF[P] + u*d3;   // chunk layout: u-major, k inner
  #pragma unroll
  for (int k=0;k<d3;++k) zp[k] = acc[k];
}

__global__ __launch_bounds__(256) void tp_main(const float* __restrict__ x,
                                               const float* __restrict__ y,
                                               float* __restrict__ out,
                                               int nrow){
  const int u = threadIdx.x & 63;
  int row = blockIdx.x*4 + (threadIdx.x>>6);
  row = __builtin_amdgcn_readfirstlane(row);   // provably wave-uniform
  if (row >= nrow) return;

  const float* xr = x + (size_t)row*XD;
  const float* yr = y + (size_t)row*YD;
  float*       zr = out + (size_t)row*ZD;

  float yv[9];
  #pragma unroll
  for (int j=0;j<9;++j) yv[j] = yr[j];

  float xv0 = xr[u];          // l=0 block: x[n, u]
  float xv1[3];
  #pragma unroll
  for (int i=0;i<3;++i) xv1[i] = xr[64 + 3*u + i];   // l=1 block
  float xv2[5];
  #pragma unroll
  for (int i=0;i<5;++i) xv2[i] = xr[256 + 5*u + i];  // l=2 block

  do_path< 0>(xv0,xv1,xv2,yv,zr,u);
  do_path< 1>(xv0,xv1,xv2,yv,zr,u);
  do_path< 2>(xv0,xv1,xv2,yv,zr,u);
  do_path< 3>(xv0,xv1,xv2,yv,zr,u);
  do_path< 4>(xv0,xv1,xv2,yv,zr,u);
  do_path< 5>(xv0,xv1,xv2,yv,zr,u);
  do_path< 6>(xv0,xv1,xv2,yv,zr,u);
  do_path< 7>(xv0,xv1,xv2,yv,zr,u);
  do_path< 8>(xv0,xv1,xv2,yv,zr,u);
  do_path< 9>(xv0,xv1,xv2,yv,zr,u);
  do_path<10>(xv0,xv1,xv2,yv,zr,u);
  do_path<11>(xv0,xv1,xv2,yv,zr,u);
  do_path<12>(xv0,xv1,xv2,yv,zr,u);
  do_path<13>(xv0,xv1,xv2,yv,zr,u);
  do_path<14>(xv0,xv1,xv2,yv,zr,u);
  do_path<15>(xv0,xv1,xv2,yv,zr,u);
  do_path<16>(xv0,xv1,xv2,yv,zr,u);
  do_path<17>(xv0,xv1,xv2,yv,zr,u);
  do_path<18>(xv0,xv1,xv2,yv,zr,u);
}

// ------------------------------ launch -------------------------------------

extern "C" void kernel_launch(void* const* d_in, const int* in_sizes, int n_in,
                              void* d_out, int out_size, void* d_ws, size_t ws_size,
                              hipStream_t stream) {
  const float* x = (const float*)d_in[0];
  const float* y = (const float*)d_in[1];
  float* out = (float*)d_out;
  const int nrow = in_sizes[0] / XD;   // 32768
  const int nb = (nrow + 3) / 4;       // 4 rows (4 waves) per block
  hipLaunchKernelGGL(tp_main, dim3(nb), dim3(256), 0, stream, x, y, out, nrow);
}

// Round 5
// 710.038 us; speedup vs baseline: 1.0664x; 1.0664x over previous
//
#include <hip/hip_runtime.h>

// ---------------------------------------------------------------------------
// e3nn-style tensor product:  X irreps 64x(l=0,1,2)  (x)  Y irreps 1x(l=0,1,2)
// 19 output paths, per-row out dim 5184, N=32768 rows.
// Memory-bound target (679 MB write + 77 MB read -> ~125 us floor at 6.3 TB/s).
//
// v2 insight: removing all w3j LDS reads changed nothing -> bottleneck is the
// STORE pattern (lane-stride 4*d3 B scalar stores = ~5x partial-line
// transaction inflation). v3 added a per-path intra-wave LDS transpose but
// FAILED correctness: cross-lane exchange through LDS without a fence is a
// compiler-level data race (per-thread memory model -> hipcc may reorder the
// ds_reads around the ds_writes; same hazard class as guide rule #18).
// v4 = v3 + zero-cost ordering fences:
//   writes -> asm("s_waitcnt lgkmcnt(0)":::"memory") -> reads -> asm(:::"memory")
// HW DS pipe is in-order per wave; the fences pin the COMPILER ordering.
// ---------------------------------------------------------------------------

#define NP 19

constexpr int P_L1[NP]  = {0,0,0, 1,1,1,1,1,1,1, 2,2,2,2,2,2,2,2,2};
constexpr int P_L2[NP]  = {0,1,2, 0,1,1,1,2,2,2, 0,1,1,1,2,2,2,2,2};
constexpr int P_L3[NP]  = {0,1,2, 1,0,1,2,1,2,3, 2,1,2,3,0,1,2,3,4};
// output chunk offsets within a row (chunk size 64*d3; total 5184)
constexpr int P_ZOFF[NP] = {0,64,256,576,768,832,1024,1344,1536,1856,2304,2624,2816,3136,3584,3648,3840,4160,4608};
constexpr int XD = 576, YD = 9, ZD = 5184;

// ------------------- compile-time Wigner-3j (mirrors reference) ------------

constexpr double dfact(int n){ double r=1.0; for(int i=2;i<=n;++i) r*=(double)i; return r; }
constexpr double cabs_(double x){ return x<0.0 ? -x : x; }

constexpr double csqrt(double x){
  if (x<=0.0) return 0.0;
  double y = x>1.0 ? x : 1.0;
  for (int i=0;i<50;++i){                      // Newton; early-exit at convergence
    double ny = 0.5*(y + x/y);
    if (ny == y) break;
    y = ny;
  }
  return y;
}

// Condon-Shortley CG <j1 m1 j2 m2 | j3 m3> (Racah) -- exact mirror of _cg()
constexpr double cgc(int j1,int m1,int j2,int m2,int j3,int m3){
  if (m1+m2 != m3) return 0.0;
  double pre = (double)(2*j3+1) * dfact(j3+j1-j2)*dfact(j3-j1+j2)*dfact(j1+j2-j3)/dfact(j1+j2+j3+1);
  pre *= dfact(j3+m3)*dfact(j3-m3)*dfact(j1-m1)*dfact(j1+m1)*dfact(j2-m2)*dfact(j2+m2);
  double s = 0.0;
  for (int k=0;k<=j1+j2-j3;++k){
    int d0=j1+j2-j3-k, d1=j1-m1-k, d2=j2+m2-k, d3=j3-j2+m1+k, d4=j3-j1-m2+k;
    if (d0<0||d1<0||d2<0||d3<0||d4<0) continue;
    double t = 1.0/(dfact(k)*dfact(d0)*dfact(d1)*dfact(d2)*dfact(d3)*dfact(d4));
    s += (k&1) ? -t : t;
  }
  return csqrt(pre)*s;
}

// complex->real SH change of basis Q(l)[r][c] -- exact mirror of _Q()
constexpr void Qv(int l,int r,int c,double& re,double& im){
  re=0.0; im=0.0;
  const double s2 = 0.70710678118654752440;
  if (r==l){ if (c==l) re=1.0; return; }
  if (r>l){ int m=r-l;
    if (c==l-m)      re = s2;
    else if (c==l+m) re = (m&1)? -s2 : s2;     // (-1)^m * s2
  } else { int m=l-r;
    if (c==l-m)      im = s2;                  // i*s2
    else if (c==l+m) im = (m&1)? s2 : -s2;     // -i*(-1)^m*s2
  }
}

struct PathTab { float v[225]; };

// real-basis w3j * alpha for one (l1,l2,l3) path -- exact mirror of w3j_init
constexpr PathTab make_path(int l1,int l2,int l3){
  PathTab t{};
  const int d1=2*l1+1, d2=2*l2+1, d3=2*l3+1;
  double Cre[25]={};
  for (int a=0;a<d1;++a) for (int b=0;b<d2;++b){
    int m1=a-l1, m2=b-l2, m3=-(m1+m2);
    int am3 = m3<0 ? -m3 : m3;
    double v = 0.0;
    if (am3 <= l3){
      v = cgc(l1,m1,l2,m2,l3,-m3) / csqrt((double)(2*l3+1));
      if ((l1-l2-m3)&1) v = -v;                // (-1)^(l1-l2-m3)
    }
    Cre[a*d2+b] = v;
  }
  double Tre[225]={}, Tim[225]={};
  for (int e=0;e<d1*d2*d3;++e){
    int i = e/(d2*d3); int r = e%(d2*d3); int j = r/d3; int k = r%d3;
    double tre=0.0, tim=0.0;
    for (int a=0;a<d1;++a) for (int b=0;b<d2;++b){
      double cr = Cre[a*d2+b];
      if (cr == 0.0) continue;
      int m3 = -((a-l1)+(b-l2));
      int c = m3 + l3;
      if (c < 0 || c >= d3) continue;
      double q1r=0,q1i=0,q2r=0,q2i=0,q3r=0,q3i=0;
      Qv(l1,i,a,q1r,q1i);
      Qv(l2,j,b,q2r,q2i);
      Qv(l3,k,c,q3r,q3i);
      double pr = q1r*q2r - q1i*q2i;
      double pi = q1r*q2i + q1i*q2r;
      tre += (pr*q3r - pi*q3i)*cr;
      tim += (pr*q3i + pi*q3r)*cr;
    }
    Tre[e]=tre; Tim[e]=tim;
  }
  double sre=0.0, sim=0.0;
  for (int e=0;e<d1*d2*d3;++e){ sre += cabs_(Tre[e]); sim += cabs_(Tim[e]); }
  const bool useim = (sim > sre);              // reference picks re if sre>=sim
  const double alpha = csqrt((double)(2*l3+1)); // component-norm factor folded in
  for (int e=0;e<d1*d2*d3;++e){
    double v = useim ? Tim[e] : Tre[e];
    t.v[e] = (float)(v*alpha);
  }
  return t;
}

// one compile-time table per path: each static member is a SEPARATE constexpr
// evaluation, keeping every evaluation well under clang's constexpr-step limit
template<int P> struct PathW { static constexpr PathTab t = make_path(P_L1[P],P_L2[P],P_L3[P]); };

// ------------------------------ main kernel --------------------------------
// one wave per row; lane u = channel (mu=64 == wavefront size).
// All w3j factors fold to inline literals; zero entries are DCE'd.
// Per-path intra-wave LDS transpose: lane u writes acc[k] at LDS[u*d3+k]
// (odd word stride -> 2 lanes/bank, conflict-free), fence, reads back at
// LDS[s*64+u] (2 lanes/bank, conflict-free), stores 256B coalesced
// wave-stores. Fences pin compiler ordering; DS pipe is in-order per wave.

template<int P>
__device__ __forceinline__ void do_path(float xv0, const float (&xv1)[3], const float (&xv2)[5],
                                        const float (&yv)[9], float* __restrict__ zr,
                                        float* tb, int u){
  constexpr int l1=P_L1[P], l2=P_L2[P], l3=P_L3[P];
  constexpr int d1=2*l1+1, d2=2*l2+1, d3=2*l3+1;
  constexpr int yo = (l2==0) ? 0 : (l2==1 ? 1 : 4);

  float acc[d3];
  #pragma unroll
  for (int k=0;k<d3;++k) acc[k] = 0.f;

  #pragma unroll
  for (int i=0;i<d1;++i){
    const float xi = (l1==0) ? xv0 : (l1==1 ? xv1[i] : xv2[i]);
    #pragma unroll
    for (int j=0;j<d2;++j){
      const float xy = xi * yv[yo+j];          // DCE'd if all wv below are 0
      #pragma unroll
      for (int k=0;k<d3;++k){
        const float wv = PathW<P>::t.v[(i*d2+j)*d3 + k];  // folds to literal
        if (wv != 0.0f)                        // constant-folded branch
          acc[k] = __builtin_fmaf(xy, wv, acc[k]);
      }
    }
  }

  if constexpr (d3 == 1){
    // already coalesced: lane u writes position u of the 64-float chunk
    zr[P_ZOFF[P] + u] = acc[0];
  } else {
    // cross-lane transpose through per-wave LDS scratch.
    #pragma unroll
    for (int k=0;k<d3;++k) tb[u*d3 + k] = acc[k];
    // Compiler memory fence + HW drain of the DS write queue. Without this,
    // hipcc's per-thread alias analysis may reorder the reads below around
    // the writes above (cross-lane traffic is invisible to it).
    asm volatile("s_waitcnt lgkmcnt(0)" ::: "memory");
    #pragma unroll
    for (int s=0;s<d3;++s)
      zr[P_ZOFF[P] + s*64 + u] = tb[s*64 + u]; // 256B coalesced wave-store
    // WAR fence: next path's ds_writes must not hoist above these reads.
    asm volatile("" ::: "memory");
  }
}

__global__ __launch_bounds__(256) void tp_main(const float* __restrict__ x,
                                               const float* __restrict__ y,
                                               float* __restrict__ out,
                                               int nrow){
  __shared__ float tbuf[4][576];               // 9.2 KB: one 576-f32 scratch per wave

  const int u = threadIdx.x & 63;
  const int w = threadIdx.x >> 6;
  int row = blockIdx.x*4 + w;
  row = __builtin_amdgcn_readfirstlane(row);   // provably wave-uniform
  if (row >= nrow) return;

  float* tb = tbuf[w];

  const float* xr = x + (size_t)row*XD;
  const float* yr = y + (size_t)row*YD;
  float*       zr = out + (size_t)row*ZD;

  float yv[9];
  #pragma unroll
  for (int j=0;j<9;++j) yv[j] = yr[j];

  float xv0 = xr[u];          // l=0 block: x[n, u]
  float xv1[3];
  #pragma unroll
  for (int i=0;i<3;++i) xv1[i] = xr[64 + 3*u + i];   // l=1 block
  float xv2[5];
  #pragma unroll
  for (int i=0;i<5;++i) xv2[i] = xr[256 + 5*u + i];  // l=2 block

  do_path< 0>(xv0,xv1,xv2,yv,zr,tb,u);
  do_path< 1>(xv0,xv1,xv2,yv,zr,tb,u);
  do_path< 2>(xv0,xv1,xv2,yv,zr,tb,u);
  do_path< 3>(xv0,xv1,xv2,yv,zr,tb,u);
  do_path< 4>(xv0,xv1,xv2,yv,zr,tb,u);
  do_path< 5>(xv0,xv1,xv2,yv,zr,tb,u);
  do_path< 6>(xv0,xv1,xv2,yv,zr,tb,u);
  do_path< 7>(xv0,xv1,xv2,yv,zr,tb,u);
  do_path< 8>(xv0,xv1,xv2,yv,zr,tb,u);
  do_path< 9>(xv0,xv1,xv2,yv,zr,tb,u);
  do_path<10>(xv0,xv1,xv2,yv,zr,tb,u);
  do_path<11>(xv0,xv1,xv2,yv,zr,tb,u);
  do_path<12>(xv0,xv1,xv2,yv,zr,tb,u);
  do_path<13>(xv0,xv1,xv2,yv,zr,tb,u);
  do_path<14>(xv0,xv1,xv2,yv,zr,tb,u);
  do_path<15>(xv0,xv1,xv2,yv,zr,tb,u);
  do_path<16>(xv0,xv1,xv2,yv,zr,tb,u);
  do_path<17>(xv0,xv1,xv2,yv,zr,tb,u);
  do_path<18>(xv0,xv1,xv2,yv,zr,tb,u);
}

// ------------------------------ launch -------------------------------------

extern "C" void kernel_launch(void* const* d_in, const int* in_sizes, int n_in,
                              void* d_out, int out_size, void* d_ws, size_t ws_size,
                              hipStream_t stream) {
  const float* x = (const float*)d_in[0];
  const float* y = (const float*)d_in[1];
  float* out = (float*)d_out;
  const int nrow = in_sizes[0] / XD;   // 32768
  const int nb = (nrow + 3) / 4;       // 4 rows (4 waves) per block
  hipLaunchKernelGGL(tp_main, dim3(nb), dim3(256), 0, stream, x, y, out, nrow);
}